// Round 10
// baseline (95.398 us; speedup 1.0000x reference)
//
#include <hip/hip_runtime.h>

#define NB 2
#define NC 16
#define NH 128
#define NW 256
#define NCW 32
#define HW (NH*NW)
#define PATCH_INV (1.0f/784.0f)
#define EPS_N 1e-9f

#define SW  128        // stripe width (2 stripes per row)
#define LCS 165        // L col-sum cols [x0s-3, x0s+161]
#define RCS 134        // R col-sum cols [x0s-3, x0s+130]
#define NSL 159        // L patch-stats [x0s, x0s+158]
#define NSR 128        // R patch-stats [x0s, x0s+127]
#define HBS 136        // hbuf stride; prod col g stored at 4+(g-x0s) in [1,134]

// Block = (b, y, stripe). 256 threads = 8 d-groups(4d) x 32 x-groups(4col).
// cost[b,y,x,d] = (S_LR - SL*SR/784) * invL * invR, separable 7x7 box sums.
__global__ __launch_bounds__(256, 2) void ncc_kernel(
    const float* __restrict__ L, const float* __restrict__ R, float* __restrict__ out)
{
    __shared__ float csL[LCS], cs2L[LCS], csR[RCS], cs2R[RCS];
    __shared__ float sSL[NSL + 1], sInvL[NSL + 1], sSR[NSR], sInvR[NSR];
    __shared__ float hbuf[NCW][HBS];

    // XCD swizzle: 64 consecutive lin per XCD -> 32 contiguous y-rows of one b
    const int bid = blockIdx.x;
    const int lin = (bid & 7) * 64 + (bid >> 3);
    const int b   = lin >> 8;
    const int rr  = lin & 255;
    const int y   = rr >> 1;
    const int st  = rr & 1;
    const int x0s = st * SW;

    const int t  = threadIdx.x;
    const int dg = t >> 5;            // 0..7
    const int xg = t & 31;            // 0..31
    const int x0 = x0s + (xg << 2);   // 4 output cols
    const int d0 = dg << 2;           // 4 disparities
    const int s  = x0 + d0;           // L window base, multiple of 4

    const size_t base = (size_t)b * NC * HW;

    // ---- phase A: column channel+vertical sums (299 jobs, strided) ----
    for (int j = t; j < LCS + RCS; j += 256) {
        const bool isL = j < LCS;
        const int lcl = isL ? j : (j - LCS);
        const int g = x0s - 3 + lcl;
        float a = 0.f, a2 = 0.f;
        if ((unsigned)g < NW) {
            const float* img = isL ? L : R;
            #pragma unroll
            for (int dy = -3; dy <= 3; ++dy) {
                const int yy = y + dy;
                if ((unsigned)yy < NH) {
                    const float* p = img + base + (size_t)yy * NW + g;
                    #pragma unroll
                    for (int c = 0; c < NC; ++c) {
                        float v = p[c * HW];
                        a += v; a2 += v * v;
                    }
                }
            }
        }
        if (isL) { csL[lcl] = a; cs2L[lcl] = a2; }
        else     { csR[lcl] = a; cs2R[lcl] = a2; }
    }
    __syncthreads();

    // ---- phase B: horizontal 7-tap -> patch stats (287 jobs, strided) ----
    for (int j = t; j < NSL + NSR; j += 256) {
        if (j < NSL) {
            float S = 0.f, S2 = 0.f;
            #pragma unroll
            for (int k = 0; k < 7; ++k) { S += csL[j + k]; S2 += cs2L[j + k]; }
            sSL[j]   = S;
            sInvL[j] = rsqrtf(S2 - S * S * PATCH_INV + EPS_N);
        } else {
            const int xr = j - NSL;
            float S = 0.f, S2 = 0.f;
            #pragma unroll
            for (int k = 0; k < 7; ++k) { S += csR[xr + k]; S2 += cs2R[xr + k]; }
            sSR[xr]   = S;
            sInvR[xr] = rsqrtf(S2 - S * S * PATCH_INV + EPS_N);
        }
    }
    __syncthreads();

    // ---- phase C: channel+row product sums, 4 cols x 4 disps per thread ----
    float vp[4][4];
    #pragma unroll
    for (int i = 0; i < 4; ++i)
        #pragma unroll
        for (int j = 0; j < 4; ++j) vp[i][j] = 0.f;

    #pragma unroll
    for (int dy = -3; dy <= 3; ++dy) {
        const int yy = y + dy;
        if ((unsigned)yy < NH) {
            const float* lrow = L + base + (size_t)yy * NW;
            const float* rrow = R + base + (size_t)yy * NW;
            #pragma unroll
            for (int c = 0; c < NC; ++c) {
                const float* lc = lrow + (size_t)c * HW;
                const float* rc = rrow + (size_t)c * HW;
                float4 rv4 = *(const float4*)(rc + x0);
                float rv[4] = {rv4.x, rv4.y, rv4.z, rv4.w};
                float lw[8];
                #pragma unroll
                for (int ch = 0; ch < 2; ++ch) {
                    int col  = s + ch * 4;                       // multiple of 4
                    int colc = col < (NW - 4) ? col : (NW - 4);  // always-valid addr
                    float4 lv = *(const float4*)(lc + colc);
                    bool ok = (col < NW);                        // ext region zero
                    lw[ch*4+0] = ok ? lv.x : 0.f;
                    lw[ch*4+1] = ok ? lv.y : 0.f;
                    lw[ch*4+2] = ok ? lv.z : 0.f;
                    lw[ch*4+3] = ok ? lv.w : 0.f;
                }
                #pragma unroll
                for (int xx = 0; xx < 4; ++xx)
                    #pragma unroll
                    for (int j = 0; j < 4; ++j)
                        vp[xx][j] += lw[xx + j] * rv[xx];
            }
        }
    }
    #pragma unroll
    for (int j = 0; j < 4; ++j)
        *(float4*)&hbuf[d0 + j][4 + (xg << 2)] =
            make_float4(vp[0][j], vp[1][j], vp[2][j], vp[3][j]);

    // ---- phase C2: halo products, rel {-3,-2,-1,128,129,130} x 32 d ----
    if (t < 192) {
        const int hi = t >> 5;                    // 0..5
        const int d  = t & 31;
        const int rel = (hi < 3) ? (hi - 3) : (125 + hi);
        const int gr = x0s + rel;
        const int gl = gr + d;
        float acc = 0.f;
        if ((unsigned)gr < NW) {
            const bool lok = gl < NW;
            const int gla = lok ? gl : 0;
            #pragma unroll
            for (int dy = -3; dy <= 3; ++dy) {
                const int yy = y + dy;
                if ((unsigned)yy < NH) {
                    const float* lrow = L + base + (size_t)yy * NW;
                    const float* rrow = R + base + (size_t)yy * NW;
                    #pragma unroll
                    for (int c = 0; c < NC; ++c) {
                        float lv = lrow[(size_t)c * HW + gla];
                        lv = lok ? lv : 0.f;
                        acc += lv * rrow[(size_t)c * HW + gr];
                    }
                }
            }
        }
        hbuf[d][4 + rel] = acc;
    }
    __syncthreads();

    // ---- phase D: horizontal 7-tap on products + normalize + store ----
    float res[4][4];
    #pragma unroll
    for (int j = 0; j < 4; ++j) {
        float w[10];
        #pragma unroll
        for (int k = 0; k < 10; ++k) w[k] = hbuf[d0 + j][(xg << 2) + 1 + k];
        #pragma unroll
        for (int xx = 0; xx < 4; ++xx) {
            float sum = 0.f;
            #pragma unroll
            for (int k = 0; k < 7; ++k) sum += w[xx + k];
            const int xel = (xg << 2) + xx + d0 + j;   // (x-x0s)+d, <= 158
            const int xrl = (xg << 2) + xx;            // x-x0s
            res[xx][j] = (sum - sSL[xel] * sSR[xrl] * PATCH_INV) * sInvL[xel] * sInvR[xrl];
        }
    }

    float* op = out + (((size_t)(b * NH + y) * NW) + x0) * NCW + d0;
    #pragma unroll
    for (int xx = 0; xx < 4; ++xx)
        *(float4*)(op + (size_t)xx * NCW) =
            make_float4(res[xx][0], res[xx][1], res[xx][2], res[xx][3]);
}

extern "C" void kernel_launch(void* const* d_in, const int* in_sizes, int n_in,
                              void* d_out, int out_size, void* d_ws, size_t ws_size,
                              hipStream_t stream) {
    const float* L = (const float*)d_in[0];
    const float* R = (const float*)d_in[1];
    float* out = (float*)d_out;
    ncc_kernel<<<dim3(NB * NH * 2), dim3(256), 0, stream>>>(L, R, out);
}